// Round 17
// baseline (246.681 us; speedup 1.0000x reference)
//
#include <hip/hip_runtime.h>

#define TPB 256
#define S_TOT 16384
#define NCHUNK 512
#define CLEN 32
#define EPS 1e-5f
#define SLOPE 0.01f

__device__ __forceinline__ float leakyf(float v){ return v > 0.f ? v : SLOPE * v; }
__device__ __forceinline__ float siluf(float v){ return v / (1.f + __expf(-v)); }

// ================= k_upc1: ConvTranspose(up half) + dc1(1x1, 64->32) fused =================
__global__ __launch_bounds__(TPB) void k_upc1(
    const float* __restrict__ x1, const float* __restrict__ x2,
    const float* __restrict__ upw, const float* __restrict__ upb,
    const float* __restrict__ w1, const float* __restrict__ b1,
    float* __restrict__ c1, float* st1p) {
  __shared__ float wq[8192];
  __shared__ float sup[64*33];
  __shared__ float red[4][8][2];
  int t = threadIdx.x, bid = blockIdx.x;
  int sb = bid & 255, n = bid >> 8;
  int p = t & 63, os = t >> 6;
  int s = sb*64 + p;
  for (int i = t; i < 8192; i += TPB) wq[i] = upw[i];
  __syncthreads();
  int z = s >> 10, y = (s >> 5) & 31, x = s & 31;
  int tap = ((z & 1)*2 + (y & 1))*2 + (x & 1);
  int xb = n*65536 + (z >> 1)*256 + (y >> 1)*16 + (x >> 1);
  float xv[32];
  #pragma unroll
  for (int c = 0; c < 32; c++) xv[c] = x1[xb + c*2048];
  float up[8];
  #pragma unroll
  for (int j = 0; j < 8; j++) up[j] = upb[os*8 + j];
  #pragma unroll
  for (int c = 0; c < 32; c++) {
    #pragma unroll
    for (int j = 0; j < 8; j++)
      up[j] += xv[c] * wq[c*256 + (os*8 + j)*8 + tap];
  }
  #pragma unroll
  for (int j = 0; j < 8; j++) sup[p*33 + os*8 + j] = up[j];
  __syncthreads();
  int c0 = os*8;
  float acc[8];
  #pragma unroll
  for (int j = 0; j < 8; j++) acc[j] = b1[c0 + j];
  const float* px2 = x2 + n*32*S_TOT + s;
  #pragma unroll
  for (int i = 0; i < 32; i++) {
    float v = px2[i*S_TOT];
    #pragma unroll
    for (int j = 0; j < 8; j++) acc[j] += v * w1[(c0 + j)*64 + i];
  }
  #pragma unroll
  for (int o = 0; o < 32; o++) {
    float v = sup[p*33 + o];
    #pragma unroll
    for (int j = 0; j < 8; j++) acc[j] += v * w1[(c0 + j)*64 + 32 + o];
  }
  #pragma unroll
  for (int j = 0; j < 8; j++)
    c1[(n*32 + c0 + j)*S_TOT + s] = acc[j];
  int wv = t >> 6;
  #pragma unroll
  for (int j = 0; j < 8; j++) {
    float sm = acc[j], sq = acc[j]*acc[j];
    #pragma unroll
    for (int o = 32; o > 0; o >>= 1) { sm += __shfl_down(sm, o); sq += __shfl_down(sq, o); }
    if ((t & 63) == 0) { red[wv][j][0] = sm; red[wv][j][1] = sq; }
  }
  __syncthreads();
  if (t < 64) {
    int w2 = t >> 4, j = (t >> 1) & 7, m = t & 1;
    st1p[((n*32 + w2*8 + j)*2 + m)*256 + sb] = red[w2][j][m];
  }
}

// ================= k_conv2: 3x3x3 grouped conv, LDS-tiled normalized input =================
__global__ __launch_bounds__(TPB) void k_conv2(
    const float* __restrict__ c1, const float* __restrict__ w,
    const float* __restrict__ bias, const float* st1p,
    float* __restrict__ c2, float* st2p) {
  __shared__ float ws[432];
  __shared__ float tile[4080];
  __shared__ float smom[4][2];
  __shared__ float mrs[4][2];
  __shared__ float red[4][4][2];
  int bid = blockIdx.x, t = threadIdx.x;
  int sb = bid & 63, g = (bid >> 6) & 7, n = bid >> 9;
  int s0 = sb << 8;
  int z = s0 >> 10, y0 = (s0 >> 5) & 31;
  for (int i = t; i < 432; i += TPB) ws[i] = w[g*432 + i];
  {
    int pp = t >> 5, l = t & 31;
    if (pp < 8) {
      int j = pp & 3, m = pp >> 2;
      const float* sp = st1p + ((n*32 + g*4 + j)*2 + m)*256;
      float v = 0.f;
      #pragma unroll
      for (int k = 0; k < 8; k++) v += sp[l + 32*k];
      v += __shfl_down(v, 16); v += __shfl_down(v, 8); v += __shfl_down(v, 4);
      v += __shfl_down(v, 2);  v += __shfl_down(v, 1);
      if (l == 0) smom[j][m] = v;
    }
  }
  __syncthreads();
  if (t < 4) {
    float m = smom[t][0] * (1.f/S_TOT);
    mrs[t][0] = m; mrs[t][1] = rsqrtf(smom[t][1]*(1.f/S_TOT) - m*m + EPS);
  }
  __syncthreads();
  const float* cbase = c1 + (n*32 + g*4)*S_TOT;
  for (int i = t; i < 4080; i += TPB) {
    int ic = i / 1020, r = i - ic*1020;
    int zo = r / 340, r2 = r - zo*340;
    int yo = r2 / 34, xo = r2 - yo*34;
    int zz = z + zo - 1, yy = y0 + yo - 1, xx = xo - 1;
    float v = 0.f;
    if (zz >= 0 && zz < 16 && yy >= 0 && yy < 32 && xx >= 0 && xx < 32)
      v = leakyf((cbase[ic*S_TOT + zz*1024 + yy*32 + xx] - mrs[ic][0]) * mrs[ic][1]);
    tile[i] = v;
  }
  __syncthreads();
  int ty = t >> 5, x = t & 31;
  int s = s0 + t;
  float acc[4];
  #pragma unroll
  for (int oc = 0; oc < 4; oc++) acc[oc] = bias[g*4 + oc];
  #pragma unroll
  for (int ic = 0; ic < 4; ic++) {
    #pragma unroll
    for (int dz = 0; dz < 3; dz++) {
      #pragma unroll
      for (int dy = 0; dy < 3; dy++) {
        const float* tr = tile + ((ic*3 + dz)*10 + ty + dy)*34 + x;
        float p0 = tr[0], p1 = tr[1], p2 = tr[2];
        int wb = ic*27 + dz*9 + dy*3;
        #pragma unroll
        for (int oc = 0; oc < 4; oc++) {
          const float* wo = &ws[oc*108 + wb];
          acc[oc] += p0*wo[0] + p1*wo[1] + p2*wo[2];
        }
      }
    }
  }
  float sm[4], sq[4];
  #pragma unroll
  for (int oc = 0; oc < 4; oc++) {
    c2[(n*32 + g*4 + oc)*S_TOT + s] = acc[oc];
    sm[oc] = acc[oc]; sq[oc] = acc[oc]*acc[oc];
  }
  #pragma unroll
  for (int o = 32; o > 0; o >>= 1) {
    #pragma unroll
    for (int oc = 0; oc < 4; oc++) {
      sm[oc] += __shfl_down(sm[oc], o);
      sq[oc] += __shfl_down(sq[oc], o);
    }
  }
  int lane = t & 63, wv = t >> 6;
  if (lane == 0) {
    #pragma unroll
    for (int oc = 0; oc < 4; oc++) { red[wv][oc][0] = sm[oc]; red[wv][oc][1] = sq[oc]; }
  }
  __syncthreads();
  if (t < 8) {
    int oc = t & 3, m = t >> 2;
    float a = red[0][oc][m] + red[1][oc][m] + red[2][oc][m] + red[3][oc][m];
    st2p[((n*32 + g*4 + oc)*2 + m)*64 + sb] = a;
  }
}

// ================= k_conv3: 1x1 conv 32->32, IN(c2)+leaky on read, 8 oc/thread =================
__global__ __launch_bounds__(TPB) void k_conv3(
    const float* __restrict__ c2, const float* __restrict__ w,
    const float* __restrict__ bias, const float* st2p,
    float* __restrict__ c3, float* st3p) {
  __shared__ float ws[256];
  __shared__ float ssum[32][2];
  __shared__ float mrs[32][2];
  __shared__ float red[4][8][2];
  int t = threadIdx.x;
  int idx = blockIdx.x * TPB + t;
  int s = idx & 16383;
  int n = (idx >> 14) & 1;
  int q = idx >> 15;
  int sb = blockIdx.x & 63;
  int c0 = q*8;
  if (t < 256) ws[t] = w[c0*32 + t];
  if (t < 64) {
    int c = t >> 1, m = t & 1;
    const float* sp = st2p + ((n*32 + c)*2 + m)*64;
    float v = 0.f;
    #pragma unroll
    for (int k = 0; k < 64; k++) v += sp[k];
    ssum[c][m] = v;
  }
  __syncthreads();
  if (t < 32) {
    float m = ssum[t][0] * (1.f/S_TOT);
    mrs[t][0] = m; mrs[t][1] = rsqrtf(ssum[t][1]*(1.f/S_TOT) - m*m + EPS);
  }
  __syncthreads();
  const float* pin = c2 + n*32*S_TOT + s;
  float acc[8];
  #pragma unroll
  for (int j = 0; j < 8; j++) acc[j] = bias[c0 + j];
  #pragma unroll
  for (int i = 0; i < 32; i++) {
    float v = leakyf((pin[i*S_TOT] - mrs[i][0]) * mrs[i][1]);
    #pragma unroll
    for (int j = 0; j < 8; j++) acc[j] += v * ws[j*32 + i];
  }
  #pragma unroll
  for (int j = 0; j < 8; j++)
    c3[(n*32 + c0 + j)*S_TOT + s] = acc[j];
  int wv = t >> 6;
  #pragma unroll
  for (int j = 0; j < 8; j++) {
    float sm = acc[j], sq = acc[j]*acc[j];
    #pragma unroll
    for (int o = 32; o > 0; o >>= 1) { sm += __shfl_down(sm, o); sq += __shfl_down(sq, o); }
    if ((t & 63) == 0) { red[wv][j][0] = sm; red[wv][j][1] = sq; }
  }
  __syncthreads();
  if (t < 16) {
    int j = t >> 1, m = t & 1;
    float a = red[0][j][m] + red[1][j][m] + red[2][j][m] + red[3][j][m];
    st3p[((n*32 + c0 + j)*2 + m)*64 + sb] = a;
  }
}

// ================= k_token: IN+LN+in_proj + conv1d + SiLU + x_proj + dt + scan-phase1 =================
// 32-token tiles, 1024 blocks; block == one scan chunk. Aggregate layout [b][chunk][e=4t]:
// phase-8 store = one contiguous float4 per thread.
__global__ __launch_bounds__(TPB) void k_token(
    const float* __restrict__ c3, const float* st3p,
    const float* __restrict__ lnw, const float* __restrict__ lnb,
    const float* __restrict__ ipw, const float* __restrict__ c1w,
    const float* __restrict__ c1b, const float* __restrict__ xpw,
    const float* __restrict__ dtw, const float* __restrict__ dtbi,
    const float* __restrict__ Alog,
    float* __restrict__ zb, float* __restrict__ u, float* __restrict__ dt,
    float* __restrict__ Bb, float* __restrict__ Cc,
    float* __restrict__ cA, float* __restrict__ cX) {
  __shared__ float un[4224];
  __shared__ float xpf[3264];     // [f(48)][dd(68)], rows>=34 & cols>=64 zeroed
  __shared__ float sxi[2240];     // [lt(35)][ch(64)]; phase8: sdt2[32*64]
  __shared__ float lnwb[64];
  __shared__ float mrs[64];
  __shared__ float ssum[64];
  float* Wraw = un;
  float* tk   = un;               // stride 36, 35 rows
  float* mv   = un + 1280;        // 70
  float* su2  = un;               // stride 68, 32 rows
  float* xd   = un + 2176;        // 32*34
  float* sdt2 = sxi;              // 32*64, aliases sxi (dead after phase 5/6)

  int t = threadIdx.x, bid = blockIdx.x;
  int tok0 = bid * 32;
  int n = tok0 >> 14, s0 = tok0 & 16383;
  int chunk = bid & (NCHUNK - 1);

  // --- phase 0: staging ---
  if (t < 64) {
    int c = t >> 1, m = t & 1;
    const float* sp = st3p + ((n*32 + c)*2 + m)*64;
    float v = 0.f;
    #pragma unroll
    for (int k = 0; k < 64; k++) v += sp[k];
    ssum[c*2 + m] = v;
  }
  for (int i = t; i < 4096; i += TPB) {
    int f = i >> 5, c = i & 31;
    Wraw[f*33 + c] = ipw[i];
  }
  for (int i = t; i < 3264; i += TPB) {
    int f = i / 68, dd = i - f*68;
    xpf[i] = (f < 34 && dd < 64) ? xpw[f*64 + dd] : 0.f;
  }
  if (t < 32) { lnwb[t] = lnw[t]; lnwb[32 + t] = lnb[t]; }
  __syncthreads();
  // --- phase 1: mrs + per-thread weight-column extraction (S1/S2 free) ---
  if (t < 32) {
    float m = ssum[t*2] * (1.f/S_TOT);
    mrs[t*2] = m; mrs[t*2 + 1] = rsqrtf(ssum[t*2 + 1]*(1.f/S_TOT) - m*m + EPS);
  }
  int fr = t & 127, half = t >> 7;
  float wreg[32];
  float S1 = 0.f, S2 = 0.f;
  #pragma unroll
  for (int c = 0; c < 32; c++) {
    float wa = Wraw[fr*33 + c];
    wreg[c] = wa * lnwb[c];
    S1 += wreg[c];
    S2 += wa * lnwb[32 + c];
  }
  __syncthreads();               // Wraw region free
  // --- phase 2: stage tk (IN+leaky) ---
  for (int i = t; i < 1120; i += TPB) {
    int c = i / 35, lt = i - c*35;
    int sg = s0 - 3 + lt;
    int sgc = sg < 0 ? 0 : sg;
    float raw = c3[(n*32 + c)*S_TOT + sgc];
    tk[lt*36 + c] = leakyf((raw - mrs[c*2]) * mrs[c*2 + 1]);
  }
  __syncthreads();
  // --- phase 3: LN stats ---
  if (t < 35) {
    float mean = 0.f;
    #pragma unroll
    for (int c = 0; c < 32; c++) mean += tk[t*36 + c];
    mean *= (1.f/32.f);
    float var = 0.f;
    #pragma unroll
    for (int c = 0; c < 32; c++) { float d2 = tk[t*36 + c] - mean; var += d2*d2; }
    mv[t*2] = mean; mv[t*2 + 1] = rsqrtf(var*(1.f/32.f) + EPS);
  }
  __syncthreads();
  // --- phase 4: in_proj GEMM, register weights + broadcast float4 tk rows ---
  for (int lt = half; lt < 35; lt += 2) {
    float acc = 0.f;
    #pragma unroll
    for (int c4 = 0; c4 < 8; c4++) {
      float4 tq = *(const float4*)(tk + lt*36 + 4*c4);
      acc += wreg[4*c4]*tq.x + wreg[4*c4+1]*tq.y + wreg[4*c4+2]*tq.z + wreg[4*c4+3]*tq.w;
    }
    float mean = mv[lt*2], rst = mv[lt*2 + 1];
    float r = rst*(acc - mean*S1) + S2;
    int sg = s0 - 3 + lt;
    if (fr < 64) {
      sxi[lt*64 + fr] = (sg < 0) ? 0.f : r;
    } else if (lt >= 3) {
      zb[(tok0 + lt - 3)*64 + (fr - 64)] = r;
    }
  }
  __syncthreads();               // tk/mv dead; su2/xd take over un[]
  // --- phase 5: causal depthwise conv1d + SiLU ---
  int ch = t & 63;
  {
    float cw0 = c1w[ch*4], cw1 = c1w[ch*4+1], cw2 = c1w[ch*4+2], cw3 = c1w[ch*4+3];
    float cb = c1b[ch];
    #pragma unroll
    for (int r = 0; r < 8; r++) {
      int lt = (t >> 6) + 4*r;
      float acc = cb + sxi[lt*64 + ch]*cw0 + sxi[(lt+1)*64 + ch]*cw1
                     + sxi[(lt+2)*64 + ch]*cw2 + sxi[(lt+3)*64 + ch]*cw3;
      float uv = siluf(acc);
      u[(tok0 + lt)*64 + ch] = uv;
      su2[lt*68 + ch] = uv;
    }
  }
  __syncthreads();
  // --- phase 6: x_proj, b128 LDS reads; two passes of (lt16, f-triple16) ---
  #pragma unroll
  for (int pass = 0; pass < 2; pass++) {
    int lt = (t >> 4) + pass*16;
    int f0 = (t & 15)*3;
    const float* sr = su2 + lt*68;
    const float* xr0 = xpf + f0*68;
    const float* xr1 = xpf + (f0+1)*68;
    const float* xr2 = xpf + (f0+2)*68;
    float a0 = 0.f, a1 = 0.f, a2 = 0.f;
    #pragma unroll
    for (int c4 = 0; c4 < 16; c4++) {
      float4 uq = *(const float4*)(sr + 4*c4);
      float4 q0 = *(const float4*)(xr0 + 4*c4);
      float4 q1 = *(const float4*)(xr1 + 4*c4);
      float4 q2 = *(const float4*)(xr2 + 4*c4);
      a0 += uq.x*q0.x + uq.y*q0.y + uq.z*q0.z + uq.w*q0.w;
      a1 += uq.x*q1.x + uq.y*q1.y + uq.z*q1.z + uq.w*q1.w;
      a2 += uq.x*q2.x + uq.y*q2.y + uq.z*q2.z + uq.w*q2.w;
    }
    if (f0     < 34) xd[lt*34 + f0]     = a0;
    if (f0 + 1 < 34) xd[lt*34 + f0 + 1] = a1;
    if (f0 + 2 < 34) xd[lt*34 + f0 + 2] = a2;
  }
  __syncthreads();               // sxi dead past here -> sdt2 takes over
  // --- phase 7: dt softplus (global + LDS mirror) + B/C emit ---
  {
    float dw0 = dtw[ch*2], dw1 = dtw[ch*2+1], db = dtbi[ch];
    #pragma unroll
    for (int r = 0; r < 8; r++) {
      int lt = (t >> 6) + 4*r;
      int token = tok0 + lt;
      float dv = xd[lt*34]*dw0 + xd[lt*34 + 1]*dw1 + db;
      float sp = fmaxf(dv, 0.f) + log1pf(__expf(-fabsf(dv)));
      dt[token*64 + ch] = sp;
      sdt2[lt*64 + ch] = sp;
      if (ch < 16)      Bb[token*16 + ch]      = xd[lt*34 + 2 + ch];
      else if (ch < 32) Cc[token*16 + ch - 16] = xd[lt*34 + 2 + ch];
    }
  }
  __syncthreads();
  // --- phase 8: local chunk scan, contiguous float4 aggregate store ---
  {
    int q = t & 3, d = t >> 2;
    float Ar0 = -__expf(Alog[d*16 + 4*q]);
    float Ar1 = -__expf(Alog[d*16 + 4*q + 1]);
    float Ar2 = -__expf(Alog[d*16 + 4*q + 2]);
    float Ar3 = -__expf(Alog[d*16 + 4*q + 3]);
    float h0 = 0.f, h1 = 0.f, h2 = 0.f, h3 = 0.f, sdts = 0.f;
    #pragma unroll 4
    for (int tt = 0; tt < CLEN; tt++) {
      float dtv = sdt2[tt*64 + d], uv = su2[tt*68 + d];
      sdts += dtv;
      float du = dtv * uv;
      const float* bp = xd + tt*34 + 2 + 4*q;
      float B0 = bp[0], B1 = bp[1], B2 = bp[2], B3 = bp[3];
      h0 = __expf(Ar0*dtv)*h0 + B0*du;
      h1 = __expf(Ar1*dtv)*h1 + B1*du;
      h2 = __expf(Ar2*dtv)*h2 + B2*du;
      h3 = __expf(Ar3*dtv)*h3 + B3*du;
    }
    int base = (n*NCHUNK + chunk)*1024 + 4*t;
    float4 av; av.x = __expf(Ar0*sdts); av.y = __expf(Ar1*sdts);
    av.z = __expf(Ar2*sdts); av.w = __expf(Ar3*sdts);
    float4 xv4; xv4.x = h0; xv4.y = h1; xv4.z = h2; xv4.w = h3;
    *(float4*)(cA + base) = av;
    *(float4*)(cX + base) = xv4;
  }
}

// aggregate layout: [b][chunk][e], e = d*16+nn, NCHUNK=512

// ================= scan phase 2: serial thread-per-(b,e), fully coalesced =================
// 2048 threads (8 blocks); at each chunk step a wave reads 64 consecutive e -> 256B segments.
__global__ __launch_bounds__(TPB) void k_scan2(
    const float* __restrict__ cA, float* __restrict__ cX) {
  int tid = blockIdx.x*TPB + threadIdx.x;   // 0..2047
  int b = tid >> 10, e = tid & 1023;
  size_t base = (size_t)b*NCHUNK*1024 + e;
  float h = 0.f;
  #pragma unroll 8
  for (int c = 0; c < NCHUNK; c++) {
    size_t idx = base + (size_t)c*1024;
    float a = cA[idx], x = cX[idx];
    cX[idx] = h;
    h = a*h + x;
  }
}

// ================= scan phase 3: 32-token chunks, seeded replay + gate + out_proj =================
__global__ __launch_bounds__(TPB) void k_scan3(
    const float* __restrict__ dt, const float* __restrict__ u,
    const float* __restrict__ Bb, const float* __restrict__ Cc,
    const float* __restrict__ Alog, const float* __restrict__ Dp,
    const float* __restrict__ zb, const float* __restrict__ cX,
    const float* __restrict__ opw, float* __restrict__ out) {
  __shared__ __align__(16) float sdt[1024], su[1024], sB[256], sC[256];
  __shared__ float gt[32*65];
  int bid = blockIdx.x, t = threadIdx.x;
  int chunk = bid & (NCHUNK-1), b = bid >> 9;
  int q = t & 3, d = t >> 2;
  float Ar[4];
  #pragma unroll
  for (int j = 0; j < 4; j++) Ar[j] = -__expf(Alog[d*16 + 4*q + j]);
  float h[4];
  {
    float4 hs = *(const float4*)(cX + (size_t)(b*NCHUNK + chunk)*1024 + 4*t);
    h[0] = hs.x; h[1] = hs.y; h[2] = hs.z; h[3] = hs.w;
  }
  float Dv = Dp[d];
  int tg0 = b*S_TOT + chunk*CLEN;
  for (int tile = 0; tile < 2; tile++) {
    int base = tg0 + tile*16;
    {
      int i = t*4;
      *(float4*)(sdt + i) = *(const float4*)(dt + base*64 + i);
      *(float4*)(su  + i) = *(const float4*)(u  + base*64 + i);
    }
    for (int i = t; i < 1024; i += TPB)
      gt[(tile*16 + (i >> 6))*65 + (i & 63)] = zb[base*64 + i];
    sB[t] = Bb[base*16 + t];
    sC[t] = Cc[base*16 + t];
    __syncthreads();
    #pragma unroll
    for (int tt = 0; tt < 16; tt++) {
      float dtv = sdt[tt*64 + d], uv = su[tt*64 + d];
      float du = dtv * uv;
      float4 Bq = *(const float4*)(sB + tt*16 + q*4);
      float4 Cq = *(const float4*)(sC + tt*16 + q*4);
      h[0] = __expf(Ar[0]*dtv)*h[0] + Bq.x*du;
      h[1] = __expf(Ar[1]*dtv)*h[1] + Bq.y*du;
      h[2] = __expf(Ar[2]*dtv)*h[2] + Bq.z*du;
      h[3] = __expf(Ar[3]*dtv)*h[3] + Bq.w*du;
      float yp = h[0]*Cq.x + h[1]*Cq.y + h[2]*Cq.z + h[3]*Cq.w;
      yp += __shfl_xor(yp, 1);
      yp += __shfl_xor(yp, 2);
      if (q == 0) {
        float zv = gt[(tile*16 + tt)*65 + d];
        gt[(tile*16 + tt)*65 + d] = (yp + uv*Dv) * siluf(zv);
      }
    }
    __syncthreads();
  }
  // ---- fused out_proj from 32-token LDS g-tile: thread = (sl32, oc-quad8) ----
  {
    int sl = t & 31, cb = t >> 5;
    float acc[4] = {0.f,0.f,0.f,0.f};
    const float* wp = opw + cb*4*64;
    #pragma unroll
    for (int dd = 0; dd < 64; dd++) {
      float v = gt[sl*65 + dd];
      #pragma unroll
      for (int j = 0; j < 4; j++) acc[j] += v * wp[j*64 + dd];
    }
    #pragma unroll
    for (int j = 0; j < 4; j++)
      out[(b*32 + cb*4 + j)*S_TOT + chunk*CLEN + sl] = acc[j];
  }
}

extern "C" void kernel_launch(void* const* d_in, const int* in_sizes, int n_in,
                              void* d_out, int out_size, void* d_ws, size_t ws_size,
                              hipStream_t stream) {
  const float* x1    = (const float*)d_in[0];
  const float* x2    = (const float*)d_in[1];
  const float* upw   = (const float*)d_in[2];
  const float* upb   = (const float*)d_in[3];
  const float* dc1w  = (const float*)d_in[4];
  const float* dc1b  = (const float*)d_in[5];
  const float* dc2w  = (const float*)d_in[6];
  const float* dc2b  = (const float*)d_in[7];
  const float* dc3w  = (const float*)d_in[8];
  const float* dc3b  = (const float*)d_in[9];
  const float* lnw   = (const float*)d_in[10];
  const float* lnb   = (const float*)d_in[11];
  const float* ipw   = (const float*)d_in[12];
  const float* c1w   = (const float*)d_in[13];
  const float* c1b   = (const float*)d_in[14];
  const float* xpw   = (const float*)d_in[15];
  const float* dtw   = (const float*)d_in[16];
  const float* dtbi  = (const float*)d_in[17];
  const float* Alog  = (const float*)d_in[18];
  const float* Dp    = (const float*)d_in[19];
  const float* opw   = (const float*)d_in[20];
  float* out = (float*)d_out;

  float* ws = (float*)d_ws;
  float* st1p  = ws + 0;          // 32768
  float* st2p  = ws + 32768;      // 8192
  float* st3p  = ws + 40960;      // 8192
  float* c1    = ws + 49152;      // 1,048,576
  float* c2    = ws + 1097728;    // 1,048,576
  float* c3    = ws + 2146304;    // 1,048,576
  float* zb    = ws + 3194880;    // 2,097,152
  float* ub    = ws + 5292032;    // 2,097,152
  float* dtb   = ws + 7389184;    // 2,097,152
  float* Bb    = ws + 9486336;    // 524,288
  float* Cc    = ws + 10010624;   // 524,288
  float* cA    = ws + 10534912;   // 1,048,576
  float* cX    = ws + 11583488;   // 1,048,576

  k_upc1 <<<512,  TPB, 0, stream>>>(x1, x2, upw, upb, dc1w, dc1b, c1, st1p);
  k_conv2<<<1024, TPB, 0, stream>>>(c1, dc2w, dc2b, st1p, c2, st2p);
  k_conv3<<<512,  TPB, 0, stream>>>(c2, dc3w, dc3b, st2p, c3, st3p);
  k_token<<<1024, TPB, 0, stream>>>(c3, st3p, lnw, lnb, ipw, c1w, c1b, xpw,
                                    dtw, dtbi, Alog, zb, ub, dtb, Bb, Cc, cA, cX);
  k_scan2<<<8,    TPB, 0, stream>>>(cA, cX);
  k_scan3<<<1024, TPB, 0, stream>>>(dtb, ub, Bb, Cc, Alog, Dp, zb, cX, opw, out);
}

// Round 18
// 235.742 us; speedup vs baseline: 1.0464x; 1.0464x over previous
//
#include <hip/hip_runtime.h>

#define TPB 256
#define S_TOT 16384
#define NCHUNK 512
#define CLEN 32
#define EPS 1e-5f
#define SLOPE 0.01f

__device__ __forceinline__ float leakyf(float v){ return v > 0.f ? v : SLOPE * v; }
__device__ __forceinline__ float siluf(float v){ return v / (1.f + __expf(-v)); }

// ================= k_upc1: ConvTranspose(up half) + dc1(1x1, 64->32) fused =================
__global__ __launch_bounds__(TPB) void k_upc1(
    const float* __restrict__ x1, const float* __restrict__ x2,
    const float* __restrict__ upw, const float* __restrict__ upb,
    const float* __restrict__ w1, const float* __restrict__ b1,
    float* __restrict__ c1, float* st1p) {
  __shared__ float wq[8192];
  __shared__ float sup[64*33];
  __shared__ float red[4][8][2];
  int t = threadIdx.x, bid = blockIdx.x;
  int sb = bid & 255, n = bid >> 8;
  int p = t & 63, os = t >> 6;
  int s = sb*64 + p;
  for (int i = t; i < 8192; i += TPB) wq[i] = upw[i];
  __syncthreads();
  int z = s >> 10, y = (s >> 5) & 31, x = s & 31;
  int tap = ((z & 1)*2 + (y & 1))*2 + (x & 1);
  int xb = n*65536 + (z >> 1)*256 + (y >> 1)*16 + (x >> 1);
  float xv[32];
  #pragma unroll
  for (int c = 0; c < 32; c++) xv[c] = x1[xb + c*2048];
  float up[8];
  #pragma unroll
  for (int j = 0; j < 8; j++) up[j] = upb[os*8 + j];
  #pragma unroll
  for (int c = 0; c < 32; c++) {
    #pragma unroll
    for (int j = 0; j < 8; j++)
      up[j] += xv[c] * wq[c*256 + (os*8 + j)*8 + tap];
  }
  #pragma unroll
  for (int j = 0; j < 8; j++) sup[p*33 + os*8 + j] = up[j];
  __syncthreads();
  int c0 = os*8;
  float acc[8];
  #pragma unroll
  for (int j = 0; j < 8; j++) acc[j] = b1[c0 + j];
  const float* px2 = x2 + n*32*S_TOT + s;
  #pragma unroll
  for (int i = 0; i < 32; i++) {
    float v = px2[i*S_TOT];
    #pragma unroll
    for (int j = 0; j < 8; j++) acc[j] += v * w1[(c0 + j)*64 + i];
  }
  #pragma unroll
  for (int o = 0; o < 32; o++) {
    float v = sup[p*33 + o];
    #pragma unroll
    for (int j = 0; j < 8; j++) acc[j] += v * w1[(c0 + j)*64 + 32 + o];
  }
  #pragma unroll
  for (int j = 0; j < 8; j++)
    c1[(n*32 + c0 + j)*S_TOT + s] = acc[j];
  int wv = t >> 6;
  #pragma unroll
  for (int j = 0; j < 8; j++) {
    float sm = acc[j], sq = acc[j]*acc[j];
    #pragma unroll
    for (int o = 32; o > 0; o >>= 1) { sm += __shfl_down(sm, o); sq += __shfl_down(sq, o); }
    if ((t & 63) == 0) { red[wv][j][0] = sm; red[wv][j][1] = sq; }
  }
  __syncthreads();
  if (t < 64) {
    int w2 = t >> 4, j = (t >> 1) & 7, m = t & 1;
    st1p[((n*32 + w2*8 + j)*2 + m)*256 + sb] = red[w2][j][m];
  }
}

// ================= k_conv2: 3x3x3 grouped conv, LDS-tiled normalized input =================
__global__ __launch_bounds__(TPB) void k_conv2(
    const float* __restrict__ c1, const float* __restrict__ w,
    const float* __restrict__ bias, const float* st1p,
    float* __restrict__ c2, float* st2p) {
  __shared__ float ws[432];
  __shared__ float tile[4080];
  __shared__ float smom[4][2];
  __shared__ float mrs[4][2];
  __shared__ float red[4][4][2];
  int bid = blockIdx.x, t = threadIdx.x;
  int sb = bid & 63, g = (bid >> 6) & 7, n = bid >> 9;
  int s0 = sb << 8;
  int z = s0 >> 10, y0 = (s0 >> 5) & 31;
  for (int i = t; i < 432; i += TPB) ws[i] = w[g*432 + i];
  {
    int pp = t >> 5, l = t & 31;
    if (pp < 8) {
      int j = pp & 3, m = pp >> 2;
      const float* sp = st1p + ((n*32 + g*4 + j)*2 + m)*256;
      float v = 0.f;
      #pragma unroll
      for (int k = 0; k < 8; k++) v += sp[l + 32*k];
      v += __shfl_down(v, 16); v += __shfl_down(v, 8); v += __shfl_down(v, 4);
      v += __shfl_down(v, 2);  v += __shfl_down(v, 1);
      if (l == 0) smom[j][m] = v;
    }
  }
  __syncthreads();
  if (t < 4) {
    float m = smom[t][0] * (1.f/S_TOT);
    mrs[t][0] = m; mrs[t][1] = rsqrtf(smom[t][1]*(1.f/S_TOT) - m*m + EPS);
  }
  __syncthreads();
  const float* cbase = c1 + (n*32 + g*4)*S_TOT;
  for (int i = t; i < 4080; i += TPB) {
    int ic = i / 1020, r = i - ic*1020;
    int zo = r / 340, r2 = r - zo*340;
    int yo = r2 / 34, xo = r2 - yo*34;
    int zz = z + zo - 1, yy = y0 + yo - 1, xx = xo - 1;
    float v = 0.f;
    if (zz >= 0 && zz < 16 && yy >= 0 && yy < 32 && xx >= 0 && xx < 32)
      v = leakyf((cbase[ic*S_TOT + zz*1024 + yy*32 + xx] - mrs[ic][0]) * mrs[ic][1]);
    tile[i] = v;
  }
  __syncthreads();
  int ty = t >> 5, x = t & 31;
  int s = s0 + t;
  float acc[4];
  #pragma unroll
  for (int oc = 0; oc < 4; oc++) acc[oc] = bias[g*4 + oc];
  #pragma unroll
  for (int ic = 0; ic < 4; ic++) {
    #pragma unroll
    for (int dz = 0; dz < 3; dz++) {
      #pragma unroll
      for (int dy = 0; dy < 3; dy++) {
        const float* tr = tile + ((ic*3 + dz)*10 + ty + dy)*34 + x;
        float p0 = tr[0], p1 = tr[1], p2 = tr[2];
        int wb = ic*27 + dz*9 + dy*3;
        #pragma unroll
        for (int oc = 0; oc < 4; oc++) {
          const float* wo = &ws[oc*108 + wb];
          acc[oc] += p0*wo[0] + p1*wo[1] + p2*wo[2];
        }
      }
    }
  }
  float sm[4], sq[4];
  #pragma unroll
  for (int oc = 0; oc < 4; oc++) {
    c2[(n*32 + g*4 + oc)*S_TOT + s] = acc[oc];
    sm[oc] = acc[oc]; sq[oc] = acc[oc]*acc[oc];
  }
  #pragma unroll
  for (int o = 32; o > 0; o >>= 1) {
    #pragma unroll
    for (int oc = 0; oc < 4; oc++) {
      sm[oc] += __shfl_down(sm[oc], o);
      sq[oc] += __shfl_down(sq[oc], o);
    }
  }
  int lane = t & 63, wv = t >> 6;
  if (lane == 0) {
    #pragma unroll
    for (int oc = 0; oc < 4; oc++) { red[wv][oc][0] = sm[oc]; red[wv][oc][1] = sq[oc]; }
  }
  __syncthreads();
  if (t < 8) {
    int oc = t & 3, m = t >> 2;
    float a = red[0][oc][m] + red[1][oc][m] + red[2][oc][m] + red[3][oc][m];
    st2p[((n*32 + g*4 + oc)*2 + m)*64 + sb] = a;
  }
}

// ================= k_conv3: 1x1 conv 32->32, IN(c2)+leaky on read, 8 oc/thread =================
__global__ __launch_bounds__(TPB) void k_conv3(
    const float* __restrict__ c2, const float* __restrict__ w,
    const float* __restrict__ bias, const float* st2p,
    float* __restrict__ c3, float* st3p) {
  __shared__ float ws[256];
  __shared__ float ssum[32][2];
  __shared__ float mrs[32][2];
  __shared__ float red[4][8][2];
  int t = threadIdx.x;
  int idx = blockIdx.x * TPB + t;
  int s = idx & 16383;
  int n = (idx >> 14) & 1;
  int q = idx >> 15;
  int sb = blockIdx.x & 63;
  int c0 = q*8;
  if (t < 256) ws[t] = w[c0*32 + t];
  if (t < 64) {
    int c = t >> 1, m = t & 1;
    const float* sp = st2p + ((n*32 + c)*2 + m)*64;
    float v = 0.f;
    #pragma unroll
    for (int k = 0; k < 64; k++) v += sp[k];
    ssum[c][m] = v;
  }
  __syncthreads();
  if (t < 32) {
    float m = ssum[t][0] * (1.f/S_TOT);
    mrs[t][0] = m; mrs[t][1] = rsqrtf(ssum[t][1]*(1.f/S_TOT) - m*m + EPS);
  }
  __syncthreads();
  const float* pin = c2 + n*32*S_TOT + s;
  float acc[8];
  #pragma unroll
  for (int j = 0; j < 8; j++) acc[j] = bias[c0 + j];
  #pragma unroll
  for (int i = 0; i < 32; i++) {
    float v = leakyf((pin[i*S_TOT] - mrs[i][0]) * mrs[i][1]);
    #pragma unroll
    for (int j = 0; j < 8; j++) acc[j] += v * ws[j*32 + i];
  }
  #pragma unroll
  for (int j = 0; j < 8; j++)
    c3[(n*32 + c0 + j)*S_TOT + s] = acc[j];
  int wv = t >> 6;
  #pragma unroll
  for (int j = 0; j < 8; j++) {
    float sm = acc[j], sq = acc[j]*acc[j];
    #pragma unroll
    for (int o = 32; o > 0; o >>= 1) { sm += __shfl_down(sm, o); sq += __shfl_down(sq, o); }
    if ((t & 63) == 0) { red[wv][j][0] = sm; red[wv][j][1] = sq; }
  }
  __syncthreads();
  if (t < 16) {
    int j = t >> 1, m = t & 1;
    float a = red[0][j][m] + red[1][j][m] + red[2][j][m] + red[3][j][m];
    st3p[((n*32 + c0 + j)*2 + m)*64 + sb] = a;
  }
}

// ================= k_token: IN+LN+in_proj + conv1d + SiLU + x_proj + dt + scan-phase1 =================
// 32-token tiles, 1024 blocks; block == one scan chunk. Aggregate layout [b][chunk][e=4t].
__global__ __launch_bounds__(TPB) void k_token(
    const float* __restrict__ c3, const float* st3p,
    const float* __restrict__ lnw, const float* __restrict__ lnb,
    const float* __restrict__ ipw, const float* __restrict__ c1w,
    const float* __restrict__ c1b, const float* __restrict__ xpw,
    const float* __restrict__ dtw, const float* __restrict__ dtbi,
    const float* __restrict__ Alog,
    float* __restrict__ zb, float* __restrict__ u, float* __restrict__ dt,
    float* __restrict__ Bb, float* __restrict__ Cc,
    float* __restrict__ cA, float* __restrict__ cX) {
  __shared__ float un[4224];
  __shared__ float xpf[3264];     // [f(48)][dd(68)], rows>=34 & cols>=64 zeroed
  __shared__ float sxi[2240];     // [lt(35)][ch(64)]; phase8: sdt2[32*64]
  __shared__ float lnwb[64];
  __shared__ float mrs[64];
  __shared__ float ssum[64];
  float* Wraw = un;
  float* tk   = un;               // stride 36, 35 rows
  float* mv   = un + 1280;        // 70
  float* su2  = un;               // stride 68, 32 rows
  float* xd   = un + 2176;        // 32*34
  float* sdt2 = sxi;              // 32*64, aliases sxi (dead after phase 5/6)

  int t = threadIdx.x, bid = blockIdx.x;
  int tok0 = bid * 32;
  int n = tok0 >> 14, s0 = tok0 & 16383;
  int chunk = bid & (NCHUNK - 1);

  // --- phase 0: staging ---
  if (t < 64) {
    int c = t >> 1, m = t & 1;
    const float* sp = st3p + ((n*32 + c)*2 + m)*64;
    float v = 0.f;
    #pragma unroll
    for (int k = 0; k < 64; k++) v += sp[k];
    ssum[c*2 + m] = v;
  }
  for (int i = t; i < 4096; i += TPB) {
    int f = i >> 5, c = i & 31;
    Wraw[f*33 + c] = ipw[i];
  }
  for (int i = t; i < 3264; i += TPB) {
    int f = i / 68, dd = i - f*68;
    xpf[i] = (f < 34 && dd < 64) ? xpw[f*64 + dd] : 0.f;
  }
  if (t < 32) { lnwb[t] = lnw[t]; lnwb[32 + t] = lnb[t]; }
  __syncthreads();
  // --- phase 1: mrs + per-thread weight-column extraction (S1/S2 free) ---
  if (t < 32) {
    float m = ssum[t*2] * (1.f/S_TOT);
    mrs[t*2] = m; mrs[t*2 + 1] = rsqrtf(ssum[t*2 + 1]*(1.f/S_TOT) - m*m + EPS);
  }
  int fr = t & 127, half = t >> 7;
  float wreg[32];
  float S1 = 0.f, S2 = 0.f;
  #pragma unroll
  for (int c = 0; c < 32; c++) {
    float wa = Wraw[fr*33 + c];
    wreg[c] = wa * lnwb[c];
    S1 += wreg[c];
    S2 += wa * lnwb[32 + c];
  }
  __syncthreads();               // Wraw region free
  // --- phase 2: stage tk (IN+leaky) ---
  for (int i = t; i < 1120; i += TPB) {
    int c = i / 35, lt = i - c*35;
    int sg = s0 - 3 + lt;
    int sgc = sg < 0 ? 0 : sg;
    float raw = c3[(n*32 + c)*S_TOT + sgc];
    tk[lt*36 + c] = leakyf((raw - mrs[c*2]) * mrs[c*2 + 1]);
  }
  __syncthreads();
  // --- phase 3: LN stats ---
  if (t < 35) {
    float mean = 0.f;
    #pragma unroll
    for (int c = 0; c < 32; c++) mean += tk[t*36 + c];
    mean *= (1.f/32.f);
    float var = 0.f;
    #pragma unroll
    for (int c = 0; c < 32; c++) { float d2 = tk[t*36 + c] - mean; var += d2*d2; }
    mv[t*2] = mean; mv[t*2 + 1] = rsqrtf(var*(1.f/32.f) + EPS);
  }
  __syncthreads();
  // --- phase 4: in_proj GEMM, register weights + broadcast float4 tk rows ---
  for (int lt = half; lt < 35; lt += 2) {
    float acc = 0.f;
    #pragma unroll
    for (int c4 = 0; c4 < 8; c4++) {
      float4 tq = *(const float4*)(tk + lt*36 + 4*c4);
      acc += wreg[4*c4]*tq.x + wreg[4*c4+1]*tq.y + wreg[4*c4+2]*tq.z + wreg[4*c4+3]*tq.w;
    }
    float mean = mv[lt*2], rst = mv[lt*2 + 1];
    float r = rst*(acc - mean*S1) + S2;
    int sg = s0 - 3 + lt;
    if (fr < 64) {
      sxi[lt*64 + fr] = (sg < 0) ? 0.f : r;
    } else if (lt >= 3) {
      zb[(tok0 + lt - 3)*64 + (fr - 64)] = r;
    }
  }
  __syncthreads();               // tk/mv dead; su2/xd take over un[]
  // --- phase 5: causal depthwise conv1d + SiLU ---
  int ch = t & 63;
  {
    float cw0 = c1w[ch*4], cw1 = c1w[ch*4+1], cw2 = c1w[ch*4+2], cw3 = c1w[ch*4+3];
    float cb = c1b[ch];
    #pragma unroll
    for (int r = 0; r < 8; r++) {
      int lt = (t >> 6) + 4*r;
      float acc = cb + sxi[lt*64 + ch]*cw0 + sxi[(lt+1)*64 + ch]*cw1
                     + sxi[(lt+2)*64 + ch]*cw2 + sxi[(lt+3)*64 + ch]*cw3;
      float uv = siluf(acc);
      u[(tok0 + lt)*64 + ch] = uv;
      su2[lt*68 + ch] = uv;
    }
  }
  __syncthreads();
  // --- phase 6: x_proj, b128 LDS reads; two passes of (lt16, f-triple16) ---
  #pragma unroll
  for (int pass = 0; pass < 2; pass++) {
    int lt = (t >> 4) + pass*16;
    int f0 = (t & 15)*3;
    const float* sr = su2 + lt*68;
    const float* xr0 = xpf + f0*68;
    const float* xr1 = xpf + (f0+1)*68;
    const float* xr2 = xpf + (f0+2)*68;
    float a0 = 0.f, a1 = 0.f, a2 = 0.f;
    #pragma unroll
    for (int c4 = 0; c4 < 16; c4++) {
      float4 uq = *(const float4*)(sr + 4*c4);
      float4 q0 = *(const float4*)(xr0 + 4*c4);
      float4 q1 = *(const float4*)(xr1 + 4*c4);
      float4 q2 = *(const float4*)(xr2 + 4*c4);
      a0 += uq.x*q0.x + uq.y*q0.y + uq.z*q0.z + uq.w*q0.w;
      a1 += uq.x*q1.x + uq.y*q1.y + uq.z*q1.z + uq.w*q1.w;
      a2 += uq.x*q2.x + uq.y*q2.y + uq.z*q2.z + uq.w*q2.w;
    }
    if (f0     < 34) xd[lt*34 + f0]     = a0;
    if (f0 + 1 < 34) xd[lt*34 + f0 + 1] = a1;
    if (f0 + 2 < 34) xd[lt*34 + f0 + 2] = a2;
  }
  __syncthreads();               // sxi dead past here -> sdt2 takes over
  // --- phase 7: dt softplus (global + LDS mirror) + B/C emit ---
  {
    float dw0 = dtw[ch*2], dw1 = dtw[ch*2+1], db = dtbi[ch];
    #pragma unroll
    for (int r = 0; r < 8; r++) {
      int lt = (t >> 6) + 4*r;
      int token = tok0 + lt;
      float dv = xd[lt*34]*dw0 + xd[lt*34 + 1]*dw1 + db;
      float sp = fmaxf(dv, 0.f) + log1pf(__expf(-fabsf(dv)));
      dt[token*64 + ch] = sp;
      sdt2[lt*64 + ch] = sp;
      if (ch < 16)      Bb[token*16 + ch]      = xd[lt*34 + 2 + ch];
      else if (ch < 32) Cc[token*16 + ch - 16] = xd[lt*34 + 2 + ch];
    }
  }
  __syncthreads();
  // --- phase 8: local chunk scan, contiguous float4 aggregate store ---
  {
    int q = t & 3, d = t >> 2;
    float Ar0 = -__expf(Alog[d*16 + 4*q]);
    float Ar1 = -__expf(Alog[d*16 + 4*q + 1]);
    float Ar2 = -__expf(Alog[d*16 + 4*q + 2]);
    float Ar3 = -__expf(Alog[d*16 + 4*q + 3]);
    float h0 = 0.f, h1 = 0.f, h2 = 0.f, h3 = 0.f, sdts = 0.f;
    #pragma unroll 4
    for (int tt = 0; tt < CLEN; tt++) {
      float dtv = sdt2[tt*64 + d], uv = su2[tt*68 + d];
      sdts += dtv;
      float du = dtv * uv;
      const float* bp = xd + tt*34 + 2 + 4*q;
      float B0 = bp[0], B1 = bp[1], B2 = bp[2], B3 = bp[3];
      h0 = __expf(Ar0*dtv)*h0 + B0*du;
      h1 = __expf(Ar1*dtv)*h1 + B1*du;
      h2 = __expf(Ar2*dtv)*h2 + B2*du;
      h3 = __expf(Ar3*dtv)*h3 + B3*du;
    }
    int base = (n*NCHUNK + chunk)*1024 + 4*t;
    float4 av; av.x = __expf(Ar0*sdts); av.y = __expf(Ar1*sdts);
    av.z = __expf(Ar2*sdts); av.w = __expf(Ar3*sdts);
    float4 xv4; xv4.x = h0; xv4.y = h1; xv4.z = h2; xv4.w = h3;
    *(float4*)(cA + base) = av;
    *(float4*)(cX + base) = xv4;
  }
}

// aggregate layout: [b][chunk][e], e = d*16+nn, NCHUNK=512; 8 segments of 64 chunks per b

// ================= k_seg: segment aggregates (64-chunk compose), all reads coalesced =================
// grid 16 = b(2) x seg(8); thread t owns e = 4t..4t+3; per iteration the block reads 4KB rows.
__global__ __launch_bounds__(TPB) void k_seg(
    const float* __restrict__ cA, const float* __restrict__ cX,
    float* __restrict__ segA, float* __restrict__ segX) {
  int t = threadIdx.x, bid = blockIdx.x;
  int b = bid >> 3, seg = bid & 7;
  float A0 = 1.f, A1 = 1.f, A2 = 1.f, A3 = 1.f;
  float X0 = 0.f, X1 = 0.f, X2 = 0.f, X3 = 0.f;
  int c0 = seg*64;
  #pragma unroll 4
  for (int c = c0; c < c0 + 64; c++) {
    size_t base = (size_t)(b*NCHUNK + c)*1024 + 4*t;
    float4 a4 = *(const float4*)(cA + base);
    float4 x4 = *(const float4*)(cX + base);
    X0 = a4.x*X0 + x4.x; A0 *= a4.x;
    X1 = a4.y*X1 + x4.y; A1 *= a4.y;
    X2 = a4.z*X2 + x4.z; A2 *= a4.z;
    X3 = a4.w*X3 + x4.w; A3 *= a4.w;
  }
  int sb = (b*8 + seg)*1024 + 4*t;
  float4 av; av.x = A0; av.y = A1; av.z = A2; av.w = A3;
  float4 xv; xv.x = X0; xv.y = X1; xv.z = X2; xv.w = X3;
  *(float4*)(segA + sb) = av;
  *(float4*)(segX + sb) = xv;
}

// ================= scan phase 3: seed computed inline (seg-prefix + chunk compose) =================
__global__ __launch_bounds__(TPB) void k_scan3(
    const float* __restrict__ dt, const float* __restrict__ u,
    const float* __restrict__ Bb, const float* __restrict__ Cc,
    const float* __restrict__ Alog, const float* __restrict__ Dp,
    const float* __restrict__ zb, const float* __restrict__ cA,
    const float* __restrict__ cX,
    const float* __restrict__ segA, const float* __restrict__ segX,
    const float* __restrict__ opw, float* __restrict__ out) {
  __shared__ __align__(16) float sdt[1024], su[1024], sB[256], sC[256];
  __shared__ float gt[32*65];
  int bid = blockIdx.x, t = threadIdx.x;
  int chunk = bid & (NCHUNK-1), b = bid >> 9;
  int q = t & 3, d = t >> 2;
  float Ar[4];
  #pragma unroll
  for (int j = 0; j < 4; j++) Ar[j] = -__expf(Alog[d*16 + 4*q + j]);
  // ---- seed: compose segment prefixes, then chunks within segment ----
  float h[4] = {0.f, 0.f, 0.f, 0.f};
  int seg = chunk >> 6;
  for (int s2 = 0; s2 < seg; s2++) {
    int sb2 = (b*8 + s2)*1024 + 4*t;
    float4 sa = *(const float4*)(segA + sb2);
    float4 sx = *(const float4*)(segX + sb2);
    h[0] = sa.x*h[0] + sx.x;
    h[1] = sa.y*h[1] + sx.y;
    h[2] = sa.z*h[2] + sx.z;
    h[3] = sa.w*h[3] + sx.w;
  }
  for (int c = seg << 6; c < chunk; c++) {
    size_t base = (size_t)(b*NCHUNK + c)*1024 + 4*t;
    float4 a4 = *(const float4*)(cA + base);
    float4 x4 = *(const float4*)(cX + base);
    h[0] = a4.x*h[0] + x4.x;
    h[1] = a4.y*h[1] + x4.y;
    h[2] = a4.z*h[2] + x4.z;
    h[3] = a4.w*h[3] + x4.w;
  }
  float Dv = Dp[d];
  int tg0 = b*S_TOT + chunk*CLEN;
  for (int tile = 0; tile < 2; tile++) {
    int base = tg0 + tile*16;
    {
      int i = t*4;
      *(float4*)(sdt + i) = *(const float4*)(dt + base*64 + i);
      *(float4*)(su  + i) = *(const float4*)(u  + base*64 + i);
    }
    for (int i = t; i < 1024; i += TPB)
      gt[(tile*16 + (i >> 6))*65 + (i & 63)] = zb[base*64 + i];
    sB[t] = Bb[base*16 + t];
    sC[t] = Cc[base*16 + t];
    __syncthreads();
    #pragma unroll
    for (int tt = 0; tt < 16; tt++) {
      float dtv = sdt[tt*64 + d], uv = su[tt*64 + d];
      float du = dtv * uv;
      float4 Bq = *(const float4*)(sB + tt*16 + q*4);
      float4 Cq = *(const float4*)(sC + tt*16 + q*4);
      h[0] = __expf(Ar[0]*dtv)*h[0] + Bq.x*du;
      h[1] = __expf(Ar[1]*dtv)*h[1] + Bq.y*du;
      h[2] = __expf(Ar[2]*dtv)*h[2] + Bq.z*du;
      h[3] = __expf(Ar[3]*dtv)*h[3] + Bq.w*du;
      float yp = h[0]*Cq.x + h[1]*Cq.y + h[2]*Cq.z + h[3]*Cq.w;
      yp += __shfl_xor(yp, 1);
      yp += __shfl_xor(yp, 2);
      if (q == 0) {
        float zv = gt[(tile*16 + tt)*65 + d];
        gt[(tile*16 + tt)*65 + d] = (yp + uv*Dv) * siluf(zv);
      }
    }
    __syncthreads();
  }
  // ---- fused out_proj from 32-token LDS g-tile: thread = (sl32, oc-quad8) ----
  {
    int sl = t & 31, cb = t >> 5;
    float acc[4] = {0.f,0.f,0.f,0.f};
    const float* wp = opw + cb*4*64;
    #pragma unroll
    for (int dd = 0; dd < 64; dd++) {
      float v = gt[sl*65 + dd];
      #pragma unroll
      for (int j = 0; j < 4; j++) acc[j] += v * wp[j*64 + dd];
    }
    #pragma unroll
    for (int j = 0; j < 4; j++)
      out[(b*32 + cb*4 + j)*S_TOT + chunk*CLEN + sl] = acc[j];
  }
}

extern "C" void kernel_launch(void* const* d_in, const int* in_sizes, int n_in,
                              void* d_out, int out_size, void* d_ws, size_t ws_size,
                              hipStream_t stream) {
  const float* x1    = (const float*)d_in[0];
  const float* x2    = (const float*)d_in[1];
  const float* upw   = (const float*)d_in[2];
  const float* upb   = (const float*)d_in[3];
  const float* dc1w  = (const float*)d_in[4];
  const float* dc1b  = (const float*)d_in[5];
  const float* dc2w  = (const float*)d_in[6];
  const float* dc2b  = (const float*)d_in[7];
  const float* dc3w  = (const float*)d_in[8];
  const float* dc3b  = (const float*)d_in[9];
  const float* lnw   = (const float*)d_in[10];
  const float* lnb   = (const float*)d_in[11];
  const float* ipw   = (const float*)d_in[12];
  const float* c1w   = (const float*)d_in[13];
  const float* c1b   = (const float*)d_in[14];
  const float* xpw   = (const float*)d_in[15];
  const float* dtw   = (const float*)d_in[16];
  const float* dtbi  = (const float*)d_in[17];
  const float* Alog  = (const float*)d_in[18];
  const float* Dp    = (const float*)d_in[19];
  const float* opw   = (const float*)d_in[20];
  float* out = (float*)d_out;

  float* ws = (float*)d_ws;
  float* st1p  = ws + 0;          // 32768
  float* st2p  = ws + 32768;      // 8192
  float* st3p  = ws + 40960;      // 8192
  float* c1    = ws + 49152;      // 1,048,576
  float* c2    = ws + 1097728;    // 1,048,576
  float* c3    = ws + 2146304;    // 1,048,576
  float* zb    = ws + 3194880;    // 2,097,152
  float* ub    = ws + 5292032;    // 2,097,152
  float* dtb   = ws + 7389184;    // 2,097,152
  float* Bb    = ws + 9486336;    // 524,288
  float* Cc    = ws + 10010624;   // 524,288
  float* cA    = ws + 10534912;   // 1,048,576
  float* cX    = ws + 11583488;   // 1,048,576
  float* segA  = ws + 12632064;   // 16,384
  float* segX  = ws + 12648448;   // 16,384

  k_upc1 <<<512,  TPB, 0, stream>>>(x1, x2, upw, upb, dc1w, dc1b, c1, st1p);
  k_conv2<<<1024, TPB, 0, stream>>>(c1, dc2w, dc2b, st1p, c2, st2p);
  k_conv3<<<512,  TPB, 0, stream>>>(c2, dc3w, dc3b, st2p, c3, st3p);
  k_token<<<1024, TPB, 0, stream>>>(c3, st3p, lnw, lnb, ipw, c1w, c1b, xpw,
                                    dtw, dtbi, Alog, zb, ub, dtb, Bb, Cc, cA, cX);
  k_seg  <<<16,   TPB, 0, stream>>>(cA, cX, segA, segX);
  k_scan3<<<1024, TPB, 0, stream>>>(dtb, ub, Bb, Cc, Alog, Dp, zb, cA, cX,
                                    segA, segX, opw, out);
}

// Round 19
// 227.073 us; speedup vs baseline: 1.0864x; 1.0382x over previous
//
#include <hip/hip_runtime.h>

#define TPB 256
#define S_TOT 16384
#define NCHUNK 512
#define CLEN 32
#define EPS 1e-5f
#define SLOPE 0.01f

__device__ __forceinline__ float leakyf(float v){ return v > 0.f ? v : SLOPE * v; }
__device__ __forceinline__ float siluf(float v){ return v / (1.f + __expf(-v)); }

// ================= k_upc1: ConvTranspose(up half) + dc1(1x1, 64->32) fused =================
__global__ __launch_bounds__(TPB) void k_upc1(
    const float* __restrict__ x1, const float* __restrict__ x2,
    const float* __restrict__ upw, const float* __restrict__ upb,
    const float* __restrict__ w1, const float* __restrict__ b1,
    float* __restrict__ c1, float* st1p) {
  __shared__ float wq[8192];
  __shared__ float sup[64*33];
  __shared__ float red[4][8][2];
  int t = threadIdx.x, bid = blockIdx.x;
  int sb = bid & 255, n = bid >> 8;
  int p = t & 63, os = t >> 6;
  int s = sb*64 + p;
  for (int i = t; i < 8192; i += TPB) wq[i] = upw[i];
  __syncthreads();
  int z = s >> 10, y = (s >> 5) & 31, x = s & 31;
  int tap = ((z & 1)*2 + (y & 1))*2 + (x & 1);
  int xb = n*65536 + (z >> 1)*256 + (y >> 1)*16 + (x >> 1);
  float xv[32];
  #pragma unroll
  for (int c = 0; c < 32; c++) xv[c] = x1[xb + c*2048];
  float up[8];
  #pragma unroll
  for (int j = 0; j < 8; j++) up[j] = upb[os*8 + j];
  #pragma unroll
  for (int c = 0; c < 32; c++) {
    #pragma unroll
    for (int j = 0; j < 8; j++)
      up[j] += xv[c] * wq[c*256 + (os*8 + j)*8 + tap];
  }
  #pragma unroll
  for (int j = 0; j < 8; j++) sup[p*33 + os*8 + j] = up[j];
  __syncthreads();
  int c0 = os*8;
  float acc[8];
  #pragma unroll
  for (int j = 0; j < 8; j++) acc[j] = b1[c0 + j];
  const float* px2 = x2 + n*32*S_TOT + s;
  #pragma unroll
  for (int i = 0; i < 32; i++) {
    float v = px2[i*S_TOT];
    #pragma unroll
    for (int j = 0; j < 8; j++) acc[j] += v * w1[(c0 + j)*64 + i];
  }
  #pragma unroll
  for (int o = 0; o < 32; o++) {
    float v = sup[p*33 + o];
    #pragma unroll
    for (int j = 0; j < 8; j++) acc[j] += v * w1[(c0 + j)*64 + 32 + o];
  }
  #pragma unroll
  for (int j = 0; j < 8; j++)
    c1[(n*32 + c0 + j)*S_TOT + s] = acc[j];
  int wv = t >> 6;
  #pragma unroll
  for (int j = 0; j < 8; j++) {
    float sm = acc[j], sq = acc[j]*acc[j];
    #pragma unroll
    for (int o = 32; o > 0; o >>= 1) { sm += __shfl_down(sm, o); sq += __shfl_down(sq, o); }
    if ((t & 63) == 0) { red[wv][j][0] = sm; red[wv][j][1] = sq; }
  }
  __syncthreads();
  if (t < 64) {
    int w2 = t >> 4, j = (t >> 1) & 7, m = t & 1;
    st1p[((n*32 + w2*8 + j)*2 + m)*256 + sb] = red[w2][j][m];
  }
}

// ================= k_conv2: 3x3x3 grouped conv, LDS-tiled normalized input =================
__global__ __launch_bounds__(TPB) void k_conv2(
    const float* __restrict__ c1, const float* __restrict__ w,
    const float* __restrict__ bias, const float* st1p,
    float* __restrict__ c2, float* st2p) {
  __shared__ float ws[432];
  __shared__ float tile[4080];
  __shared__ float smom[4][2];
  __shared__ float mrs[4][2];
  __shared__ float red[4][4][2];
  int bid = blockIdx.x, t = threadIdx.x;
  int sb = bid & 63, g = (bid >> 6) & 7, n = bid >> 9;
  int s0 = sb << 8;
  int z = s0 >> 10, y0 = (s0 >> 5) & 31;
  for (int i = t; i < 432; i += TPB) ws[i] = w[g*432 + i];
  {
    int pp = t >> 5, l = t & 31;
    if (pp < 8) {
      int j = pp & 3, m = pp >> 2;
      const float* sp = st1p + ((n*32 + g*4 + j)*2 + m)*256;
      float v = 0.f;
      #pragma unroll
      for (int k = 0; k < 8; k++) v += sp[l + 32*k];
      v += __shfl_down(v, 16); v += __shfl_down(v, 8); v += __shfl_down(v, 4);
      v += __shfl_down(v, 2);  v += __shfl_down(v, 1);
      if (l == 0) smom[j][m] = v;
    }
  }
  __syncthreads();
  if (t < 4) {
    float m = smom[t][0] * (1.f/S_TOT);
    mrs[t][0] = m; mrs[t][1] = rsqrtf(smom[t][1]*(1.f/S_TOT) - m*m + EPS);
  }
  __syncthreads();
  const float* cbase = c1 + (n*32 + g*4)*S_TOT;
  for (int i = t; i < 4080; i += TPB) {
    int ic = i / 1020, r = i - ic*1020;
    int zo = r / 340, r2 = r - zo*340;
    int yo = r2 / 34, xo = r2 - yo*34;
    int zz = z + zo - 1, yy = y0 + yo - 1, xx = xo - 1;
    float v = 0.f;
    if (zz >= 0 && zz < 16 && yy >= 0 && yy < 32 && xx >= 0 && xx < 32)
      v = leakyf((cbase[ic*S_TOT + zz*1024 + yy*32 + xx] - mrs[ic][0]) * mrs[ic][1]);
    tile[i] = v;
  }
  __syncthreads();
  int ty = t >> 5, x = t & 31;
  int s = s0 + t;
  float acc[4];
  #pragma unroll
  for (int oc = 0; oc < 4; oc++) acc[oc] = bias[g*4 + oc];
  #pragma unroll
  for (int ic = 0; ic < 4; ic++) {
    #pragma unroll
    for (int dz = 0; dz < 3; dz++) {
      #pragma unroll
      for (int dy = 0; dy < 3; dy++) {
        const float* tr = tile + ((ic*3 + dz)*10 + ty + dy)*34 + x;
        float p0 = tr[0], p1 = tr[1], p2 = tr[2];
        int wb = ic*27 + dz*9 + dy*3;
        #pragma unroll
        for (int oc = 0; oc < 4; oc++) {
          const float* wo = &ws[oc*108 + wb];
          acc[oc] += p0*wo[0] + p1*wo[1] + p2*wo[2];
        }
      }
    }
  }
  float sm[4], sq[4];
  #pragma unroll
  for (int oc = 0; oc < 4; oc++) {
    c2[(n*32 + g*4 + oc)*S_TOT + s] = acc[oc];
    sm[oc] = acc[oc]; sq[oc] = acc[oc]*acc[oc];
  }
  #pragma unroll
  for (int o = 32; o > 0; o >>= 1) {
    #pragma unroll
    for (int oc = 0; oc < 4; oc++) {
      sm[oc] += __shfl_down(sm[oc], o);
      sq[oc] += __shfl_down(sq[oc], o);
    }
  }
  int lane = t & 63, wv = t >> 6;
  if (lane == 0) {
    #pragma unroll
    for (int oc = 0; oc < 4; oc++) { red[wv][oc][0] = sm[oc]; red[wv][oc][1] = sq[oc]; }
  }
  __syncthreads();
  if (t < 8) {
    int oc = t & 3, m = t >> 2;
    float a = red[0][oc][m] + red[1][oc][m] + red[2][oc][m] + red[3][oc][m];
    st2p[((n*32 + g*4 + oc)*2 + m)*64 + sb] = a;
  }
}

// ================= k_conv3: 1x1 conv 32->32, IN(c2)+leaky on read, 8 oc/thread =================
__global__ __launch_bounds__(TPB) void k_conv3(
    const float* __restrict__ c2, const float* __restrict__ w,
    const float* __restrict__ bias, const float* st2p,
    float* __restrict__ c3, float* st3p) {
  __shared__ float ws[256];
  __shared__ float ssum[32][2];
  __shared__ float mrs[32][2];
  __shared__ float red[4][8][2];
  int t = threadIdx.x;
  int idx = blockIdx.x * TPB + t;
  int s = idx & 16383;
  int n = (idx >> 14) & 1;
  int q = idx >> 15;
  int sb = blockIdx.x & 63;
  int c0 = q*8;
  if (t < 256) ws[t] = w[c0*32 + t];
  if (t < 64) {
    int c = t >> 1, m = t & 1;
    const float* sp = st2p + ((n*32 + c)*2 + m)*64;
    float v = 0.f;
    #pragma unroll
    for (int k = 0; k < 64; k++) v += sp[k];
    ssum[c][m] = v;
  }
  __syncthreads();
  if (t < 32) {
    float m = ssum[t][0] * (1.f/S_TOT);
    mrs[t][0] = m; mrs[t][1] = rsqrtf(ssum[t][1]*(1.f/S_TOT) - m*m + EPS);
  }
  __syncthreads();
  const float* pin = c2 + n*32*S_TOT + s;
  float acc[8];
  #pragma unroll
  for (int j = 0; j < 8; j++) acc[j] = bias[c0 + j];
  #pragma unroll
  for (int i = 0; i < 32; i++) {
    float v = leakyf((pin[i*S_TOT] - mrs[i][0]) * mrs[i][1]);
    #pragma unroll
    for (int j = 0; j < 8; j++) acc[j] += v * ws[j*32 + i];
  }
  #pragma unroll
  for (int j = 0; j < 8; j++)
    c3[(n*32 + c0 + j)*S_TOT + s] = acc[j];
  int wv = t >> 6;
  #pragma unroll
  for (int j = 0; j < 8; j++) {
    float sm = acc[j], sq = acc[j]*acc[j];
    #pragma unroll
    for (int o = 32; o > 0; o >>= 1) { sm += __shfl_down(sm, o); sq += __shfl_down(sq, o); }
    if ((t & 63) == 0) { red[wv][j][0] = sm; red[wv][j][1] = sq; }
  }
  __syncthreads();
  if (t < 16) {
    int j = t >> 1, m = t & 1;
    float a = red[0][j][m] + red[1][j][m] + red[2][j][m] + red[3][j][m];
    st3p[((n*32 + c0 + j)*2 + m)*64 + sb] = a;
  }
}

// ================= k_token: IN+LN+in_proj + conv1d + SiLU + x_proj + dt + scan-phase1 =================
// 32-token tiles, 1024 blocks; block == one scan chunk (CLEN=32). Aggregate layout [e][chunk].
// NO launch-bounds pin (R14 lesson: pinning forced wreg spill).
__global__ __launch_bounds__(TPB) void k_token(
    const float* __restrict__ c3, const float* st3p,
    const float* __restrict__ lnw, const float* __restrict__ lnb,
    const float* __restrict__ ipw, const float* __restrict__ c1w,
    const float* __restrict__ c1b, const float* __restrict__ xpw,
    const float* __restrict__ dtw, const float* __restrict__ dtbi,
    const float* __restrict__ Alog,
    float* __restrict__ zb, float* __restrict__ u, float* __restrict__ dt,
    float* __restrict__ Bb, float* __restrict__ Cc,
    float* __restrict__ cA, float* __restrict__ cX) {
  __shared__ float un[4224];
  __shared__ float xpf[3264];     // [f(48)][dd(68)], rows>=34 & cols>=64 zeroed
  __shared__ float sxi[2240];     // [lt(35)][ch(64)]; phase8: sdt2[32*64]
  __shared__ float lnwb[64];
  __shared__ float mrs[64];
  __shared__ float ssum[64];
  float* Wraw = un;
  float* tk   = un;               // stride 36, 35 rows
  float* mv   = un + 1280;        // 70
  float* su2  = un;               // stride 68, 32 rows
  float* xd   = un + 2176;        // 32*34
  float* sdt2 = sxi;              // 32*64, aliases sxi (dead after phase 5/6)

  int t = threadIdx.x, bid = blockIdx.x;
  int tok0 = bid * 32;
  int n = tok0 >> 14, s0 = tok0 & 16383;
  int chunk = bid & (NCHUNK - 1);

  // --- phase 0: staging ---
  if (t < 64) {
    int c = t >> 1, m = t & 1;
    const float* sp = st3p + ((n*32 + c)*2 + m)*64;
    float v = 0.f;
    #pragma unroll
    for (int k = 0; k < 64; k++) v += sp[k];
    ssum[c*2 + m] = v;
  }
  for (int i = t; i < 4096; i += TPB) {
    int f = i >> 5, c = i & 31;
    Wraw[f*33 + c] = ipw[i];
  }
  for (int i = t; i < 3264; i += TPB) {
    int f = i / 68, dd = i - f*68;
    xpf[i] = (f < 34 && dd < 64) ? xpw[f*64 + dd] : 0.f;
  }
  if (t < 32) { lnwb[t] = lnw[t]; lnwb[32 + t] = lnb[t]; }
  __syncthreads();
  // --- phase 1: mrs + per-thread weight-column extraction (S1/S2 free) ---
  if (t < 32) {
    float m = ssum[t*2] * (1.f/S_TOT);
    mrs[t*2] = m; mrs[t*2 + 1] = rsqrtf(ssum[t*2 + 1]*(1.f/S_TOT) - m*m + EPS);
  }
  int fr = t & 127, half = t >> 7;
  float wreg[32];
  float S1 = 0.f, S2 = 0.f;
  #pragma unroll
  for (int c = 0; c < 32; c++) {
    float wa = Wraw[fr*33 + c];
    wreg[c] = wa * lnwb[c];
    S1 += wreg[c];
    S2 += wa * lnwb[32 + c];
  }
  __syncthreads();               // Wraw region free
  // --- phase 2: stage tk (IN+leaky) ---
  for (int i = t; i < 1120; i += TPB) {
    int c = i / 35, lt = i - c*35;
    int sg = s0 - 3 + lt;
    int sgc = sg < 0 ? 0 : sg;
    float raw = c3[(n*32 + c)*S_TOT + sgc];
    tk[lt*36 + c] = leakyf((raw - mrs[c*2]) * mrs[c*2 + 1]);
  }
  __syncthreads();
  // --- phase 3: LN stats ---
  if (t < 35) {
    float mean = 0.f;
    #pragma unroll
    for (int c = 0; c < 32; c++) mean += tk[t*36 + c];
    mean *= (1.f/32.f);
    float var = 0.f;
    #pragma unroll
    for (int c = 0; c < 32; c++) { float d2 = tk[t*36 + c] - mean; var += d2*d2; }
    mv[t*2] = mean; mv[t*2 + 1] = rsqrtf(var*(1.f/32.f) + EPS);
  }
  __syncthreads();
  // --- phase 4: in_proj GEMM, register weights + broadcast float4 tk rows ---
  for (int lt = half; lt < 35; lt += 2) {
    float acc = 0.f;
    #pragma unroll
    for (int c4 = 0; c4 < 8; c4++) {
      float4 tq = *(const float4*)(tk + lt*36 + 4*c4);
      acc += wreg[4*c4]*tq.x + wreg[4*c4+1]*tq.y + wreg[4*c4+2]*tq.z + wreg[4*c4+3]*tq.w;
    }
    float mean = mv[lt*2], rst = mv[lt*2 + 1];
    float r = rst*(acc - mean*S1) + S2;
    int sg = s0 - 3 + lt;
    if (fr < 64) {
      sxi[lt*64 + fr] = (sg < 0) ? 0.f : r;
    } else if (lt >= 3) {
      zb[(tok0 + lt - 3)*64 + (fr - 64)] = r;
    }
  }
  __syncthreads();               // tk/mv dead; su2/xd take over un[]
  // --- phase 5: causal depthwise conv1d + SiLU ---
  int ch = t & 63;
  {
    float cw0 = c1w[ch*4], cw1 = c1w[ch*4+1], cw2 = c1w[ch*4+2], cw3 = c1w[ch*4+3];
    float cb = c1b[ch];
    #pragma unroll
    for (int r = 0; r < 8; r++) {
      int lt = (t >> 6) + 4*r;
      float acc = cb + sxi[lt*64 + ch]*cw0 + sxi[(lt+1)*64 + ch]*cw1
                     + sxi[(lt+2)*64 + ch]*cw2 + sxi[(lt+3)*64 + ch]*cw3;
      float uv = siluf(acc);
      u[(tok0 + lt)*64 + ch] = uv;
      su2[lt*68 + ch] = uv;
    }
  }
  __syncthreads();
  // --- phase 6: x_proj, b128 LDS reads; two passes of (lt16, f-triple16) ---
  #pragma unroll
  for (int pass = 0; pass < 2; pass++) {
    int lt = (t >> 4) + pass*16;
    int f0 = (t & 15)*3;
    const float* sr = su2 + lt*68;
    const float* xr0 = xpf + f0*68;
    const float* xr1 = xpf + (f0+1)*68;
    const float* xr2 = xpf + (f0+2)*68;
    float a0 = 0.f, a1 = 0.f, a2 = 0.f;
    #pragma unroll
    for (int c4 = 0; c4 < 16; c4++) {
      float4 uq = *(const float4*)(sr + 4*c4);
      float4 q0 = *(const float4*)(xr0 + 4*c4);
      float4 q1 = *(const float4*)(xr1 + 4*c4);
      float4 q2 = *(const float4*)(xr2 + 4*c4);
      a0 += uq.x*q0.x + uq.y*q0.y + uq.z*q0.z + uq.w*q0.w;
      a1 += uq.x*q1.x + uq.y*q1.y + uq.z*q1.z + uq.w*q1.w;
      a2 += uq.x*q2.x + uq.y*q2.y + uq.z*q2.z + uq.w*q2.w;
    }
    if (f0     < 34) xd[lt*34 + f0]     = a0;
    if (f0 + 1 < 34) xd[lt*34 + f0 + 1] = a1;
    if (f0 + 2 < 34) xd[lt*34 + f0 + 2] = a2;
  }
  __syncthreads();               // sxi dead past here -> sdt2 takes over
  // --- phase 7: dt softplus (global + LDS mirror) + B/C emit ---
  {
    float dw0 = dtw[ch*2], dw1 = dtw[ch*2+1], db = dtbi[ch];
    #pragma unroll
    for (int r = 0; r < 8; r++) {
      int lt = (t >> 6) + 4*r;
      int token = tok0 + lt;
      float dv = xd[lt*34]*dw0 + xd[lt*34 + 1]*dw1 + db;
      float sp = fmaxf(dv, 0.f) + log1pf(__expf(-fabsf(dv)));
      dt[token*64 + ch] = sp;
      sdt2[lt*64 + ch] = sp;
      if (ch < 16)      Bb[token*16 + ch]      = xd[lt*34 + 2 + ch];
      else if (ch < 32) Cc[token*16 + ch - 16] = xd[lt*34 + 2 + ch];
    }
  }
  __syncthreads();
  // --- phase 8: local chunk scan (was k_scan1), thread = (q,d) ---
  {
    int q = t & 3, d = t >> 2;
    float Ar0 = -__expf(Alog[d*16 + 4*q]);
    float Ar1 = -__expf(Alog[d*16 + 4*q + 1]);
    float Ar2 = -__expf(Alog[d*16 + 4*q + 2]);
    float Ar3 = -__expf(Alog[d*16 + 4*q + 3]);
    float h0 = 0.f, h1 = 0.f, h2 = 0.f, h3 = 0.f, sdts = 0.f;
    #pragma unroll 4
    for (int tt = 0; tt < CLEN; tt++) {
      float dtv = sdt2[tt*64 + d], uv = su2[tt*68 + d];
      sdts += dtv;
      float du = dtv * uv;
      const float* bp = xd + tt*34 + 2 + 4*q;
      float B0 = bp[0], B1 = bp[1], B2 = bp[2], B3 = bp[3];
      h0 = __expf(Ar0*dtv)*h0 + B0*du;
      h1 = __expf(Ar1*dtv)*h1 + B1*du;
      h2 = __expf(Ar2*dtv)*h2 + B2*du;
      h3 = __expf(Ar3*dtv)*h3 + B3*du;
    }
    int base = (((n*64 + d)*16 + 4*q)*NCHUNK) + chunk;
    cA[base]            = __expf(Ar0*sdts); cX[base]            = h0;
    cA[base + NCHUNK]   = __expf(Ar1*sdts); cX[base + NCHUNK]   = h1;
    cA[base + 2*NCHUNK] = __expf(Ar2*sdts); cX[base + 2*NCHUNK] = h2;
    cA[base + 3*NCHUNK] = __expf(Ar3*sdts); cX[base + 3*NCHUNK] = h3;
  }
}

// aggregate layout: (((b*64+d)*16+nn)*NCHUNK + chunk), NCHUNK=512

// ================= scan phase 2: wave-per-(b,d,n), 8 chunks/lane compose + KS =================
__global__ __launch_bounds__(TPB) void k_scan2(
    const float* __restrict__ cA, float* __restrict__ cX) {
  int t = threadIdx.x;
  int w = blockIdx.x*4 + (t >> 6);
  int lane = t & 63;
  int b = w >> 10, d = (w >> 4) & 63, nn = w & 15;
  int base = ((b*64 + d)*16 + nn)*NCHUNK;
  float a[8], x[8];
  *(float4*)(a)     = *(const float4*)(cA + base + lane*8);
  *(float4*)(a + 4) = *(const float4*)(cA + base + lane*8 + 4);
  *(float4*)(x)     = *(const float4*)(cX + base + lane*8);
  *(float4*)(x + 4) = *(const float4*)(cX + base + lane*8 + 4);
  float A = 1.f, X = 0.f;
  #pragma unroll
  for (int k = 0; k < 8; k++) { X = X*a[k] + x[k]; A *= a[k]; }
  #pragma unroll
  for (int off = 1; off < 64; off <<= 1) {
    float Ap = __shfl_up(A, off);
    float Xp = __shfl_up(X, off);
    if (lane >= off) { X = A*Xp + X; A = A*Ap; }
  }
  float Xe = __shfl_up(X, 1);
  if (lane == 0) Xe = 0.f;
  float r = Xe;
  float o[8];
  #pragma unroll
  for (int k = 0; k < 8; k++) { o[k] = r; r = a[k]*r + x[k]; }
  *(float4*)(cX + base + lane*8)     = *(float4*)(o);
  *(float4*)(cX + base + lane*8 + 4) = *(float4*)(o + 4);
}

// ================= scan phase 3: 32-token chunks, seeded replay + gate + out_proj =================
__global__ __launch_bounds__(TPB) void k_scan3(
    const float* __restrict__ dt, const float* __restrict__ u,
    const float* __restrict__ Bb, const float* __restrict__ Cc,
    const float* __restrict__ Alog, const float* __restrict__ Dp,
    const float* __restrict__ zb, const float* __restrict__ cX,
    const float* __restrict__ opw, float* __restrict__ out) {
  __shared__ __align__(16) float sdt[1024], su[1024], sB[256], sC[256];
  __shared__ float gt[32*65];
  int bid = blockIdx.x, t = threadIdx.x;
  int chunk = bid & (NCHUNK-1), b = bid >> 9;
  int q = t & 3, d = t >> 2;
  float Ar[4];
  #pragma unroll
  for (int j = 0; j < 4; j++) Ar[j] = -__expf(Alog[d*16 + 4*q + j]);
  float h[4];
  #pragma unroll
  for (int j = 0; j < 4; j++)
    h[j] = cX[(((b*64 + d)*16 + 4*q + j)*NCHUNK) + chunk];
  float Dv = Dp[d];
  int tg0 = b*S_TOT + chunk*CLEN;
  for (int tile = 0; tile < 2; tile++) {
    int base = tg0 + tile*16;
    {
      int i = t*4;
      *(float4*)(sdt + i) = *(const float4*)(dt + base*64 + i);
      *(float4*)(su  + i) = *(const float4*)(u  + base*64 + i);
    }
    for (int i = t; i < 1024; i += TPB)
      gt[(tile*16 + (i >> 6))*65 + (i & 63)] = zb[base*64 + i];
    sB[t] = Bb[base*16 + t];
    sC[t] = Cc[base*16 + t];
    __syncthreads();
    #pragma unroll
    for (int tt = 0; tt < 16; tt++) {
      float dtv = sdt[tt*64 + d], uv = su[tt*64 + d];
      float du = dtv * uv;
      float4 Bq = *(const float4*)(sB + tt*16 + q*4);
      float4 Cq = *(const float4*)(sC + tt*16 + q*4);
      h[0] = __expf(Ar[0]*dtv)*h[0] + Bq.x*du;
      h[1] = __expf(Ar[1]*dtv)*h[1] + Bq.y*du;
      h[2] = __expf(Ar[2]*dtv)*h[2] + Bq.z*du;
      h[3] = __expf(Ar[3]*dtv)*h[3] + Bq.w*du;
      float yp = h[0]*Cq.x + h[1]*Cq.y + h[2]*Cq.z + h[3]*Cq.w;
      yp += __shfl_xor(yp, 1);
      yp += __shfl_xor(yp, 2);
      if (q == 0) {
        float zv = gt[(tile*16 + tt)*65 + d];
        gt[(tile*16 + tt)*65 + d] = (yp + uv*Dv) * siluf(zv);
      }
    }
    __syncthreads();
  }
  // ---- fused out_proj from 32-token LDS g-tile: thread = (sl32, oc-quad8) ----
  {
    int sl = t & 31, cb = t >> 5;
    float acc[4] = {0.f,0.f,0.f,0.f};
    const float* wp = opw + cb*4*64;
    #pragma unroll
    for (int dd = 0; dd < 64; dd++) {
      float v = gt[sl*65 + dd];
      #pragma unroll
      for (int j = 0; j < 4; j++) acc[j] += v * wp[j*64 + dd];
    }
    #pragma unroll
    for (int j = 0; j < 4; j++)
      out[(b*32 + cb*4 + j)*S_TOT + chunk*CLEN + sl] = acc[j];
  }
}

extern "C" void kernel_launch(void* const* d_in, const int* in_sizes, int n_in,
                              void* d_out, int out_size, void* d_ws, size_t ws_size,
                              hipStream_t stream) {
  const float* x1    = (const float*)d_in[0];
  const float* x2    = (const float*)d_in[1];
  const float* upw   = (const float*)d_in[2];
  const float* upb   = (const float*)d_in[3];
  const float* dc1w  = (const float*)d_in[4];
  const float* dc1b  = (const float*)d_in[5];
  const float* dc2w  = (const float*)d_in[6];
  const float* dc2b  = (const float*)d_in[7];
  const float* dc3w  = (const float*)d_in[8];
  const float* dc3b  = (const float*)d_in[9];
  const float* lnw   = (const float*)d_in[10];
  const float* lnb   = (const float*)d_in[11];
  const float* ipw   = (const float*)d_in[12];
  const float* c1w   = (const float*)d_in[13];
  const float* c1b   = (const float*)d_in[14];
  const float* xpw   = (const float*)d_in[15];
  const float* dtw   = (const float*)d_in[16];
  const float* dtbi  = (const float*)d_in[17];
  const float* Alog  = (const float*)d_in[18];
  const float* Dp    = (const float*)d_in[19];
  const float* opw   = (const float*)d_in[20];
  float* out = (float*)d_out;

  float* ws = (float*)d_ws;
  float* st1p  = ws + 0;          // 32768
  float* st2p  = ws + 32768;      // 8192
  float* st3p  = ws + 40960;      // 8192
  float* c1    = ws + 49152;      // 1,048,576
  float* c2    = ws + 1097728;    // 1,048,576
  float* c3    = ws + 2146304;    // 1,048,576
  float* zb    = ws + 3194880;    // 2,097,152
  float* ub    = ws + 5292032;    // 2,097,152
  float* dtb   = ws + 7389184;    // 2,097,152
  float* Bb    = ws + 9486336;    // 524,288
  float* Cc    = ws + 10010624;   // 524,288
  float* cA    = ws + 10534912;   // 1,048,576
  float* cX    = ws + 11583488;   // 1,048,576

  k_upc1 <<<512,  TPB, 0, stream>>>(x1, x2, upw, upb, dc1w, dc1b, c1, st1p);
  k_conv2<<<1024, TPB, 0, stream>>>(c1, dc2w, dc2b, st1p, c2, st2p);
  k_conv3<<<512,  TPB, 0, stream>>>(c2, dc3w, dc3b, st2p, c3, st3p);
  k_token<<<1024, TPB, 0, stream>>>(c3, st3p, lnw, lnb, ipw, c1w, c1b, xpw,
                                    dtw, dtbi, Alog, zb, ub, dtb, Bb, Cc, cA, cX);
  k_scan2<<<512,  TPB, 0, stream>>>(cA, cX);
  k_scan3<<<1024, TPB, 0, stream>>>(dtb, ub, Bb, Cc, Alog, Dp, zb, cX, opw, out);
}